// Round 1
// baseline (44301.474 us; speedup 1.0000x reference)
//
#include <hip/hip_runtime.h>
#include <math.h>

#define B_  32
#define T_  512
#define H_  512
#define A_  128
#define VD_ 512
#define V_  32000

__device__ __forceinline__ float sigf(float x) { return 1.f / (1.f + expf(-x)); }
__device__ __forceinline__ float dot4(float4 a, float4 b) {
    return a.x * b.x + a.y * b.y + a.z * b.z + a.w * b.w;
}

// ---------------------------------------------------------------- init state
__global__ void k_init(const float* __restrict__ h00, const float* __restrict__ c00,
                       float* __restrict__ h, float* __restrict__ c, int* __restrict__ idx) {
    int b = blockIdx.x, j = threadIdx.x;
    h[b * H_ + j] = h00[j];
    c[b * H_ + j] = c00[j];
    if (j == 0) idx[b] = 0;
}

// ------------------------------------------------- gates = x@W_ih^T + h@W_hh^T + biases
// grid 256 blocks x 256 thr; thread = (j_local<<5)|b ; 8 cols per block
__global__ void k_gates(const float* __restrict__ W_emb, const float* __restrict__ ctx,
                        const float* __restrict__ h, const int* __restrict__ idx,
                        const float* __restrict__ W_ih, const float* __restrict__ W_hh,
                        const float* __restrict__ b_ih, const float* __restrict__ b_hh,
                        float* __restrict__ gates) {
    int j = blockIdx.x * 8 + (threadIdx.x >> 5);
    int b = threadIdx.x & 31;
    const float4* emb4 = (const float4*)(W_emb + (size_t)idx[b] * H_);
    const float4* ctx4 = (const float4*)(ctx + b * VD_);
    const float4* h4   = (const float4*)(h + b * H_);
    const float4* wa   = (const float4*)(W_ih + (size_t)j * 1024);        // emb part
    const float4* wb   = wa + 128;                                        // ctx part
    const float4* wh   = (const float4*)(W_hh + (size_t)j * H_);
    float acc = b_ih[j] + b_hh[j];
#pragma unroll 8
    for (int k = 0; k < 128; k++) acc += dot4(wa[k], emb4[k]);
#pragma unroll 8
    for (int k = 0; k < 128; k++) acc += dot4(wb[k], ctx4[k]);
#pragma unroll 8
    for (int k = 0; k < 128; k++) acc += dot4(wh[k], h4[k]);
    gates[b * 2048 + j] = acc;
}

// -------------------------------- LSTM pointwise + q + energy + masked softmax
// grid B_ blocks x 512 thr. first=1: skip LSTM, use h as-is (initial attend).
__global__ void k_cell_att(const float* __restrict__ gates, float* __restrict__ h,
                           float* __restrict__ c, const float* __restrict__ Wq,
                           const float* __restrict__ bq, const float* __restrict__ key,
                           const int* __restrict__ src_lens, float* __restrict__ att,
                           int first) {
    int b = blockIdx.x, t = threadIdx.x;
    __shared__ __align__(16) float hsh[H_];
    __shared__ float qsh[A_];
    __shared__ float red[T_];

    if (!first) {
        const float* g = gates + b * 2048;
        float gi = g[t], gf = g[512 + t], gg = g[1024 + t], go = g[1536 + t];
        float c0 = c[b * H_ + t];
        float c1 = sigf(gf) * c0 + sigf(gi) * tanhf(gg);
        float h1 = sigf(go) * tanhf(c1);
        c[b * H_ + t] = c1;
        h[b * H_ + t] = h1;
        hsh[t] = h1;
    } else {
        hsh[t] = h[b * H_ + t];
    }
    __syncthreads();

    if (t < A_) {
        const float4* hv  = (const float4*)hsh;
        const float4* wq4 = (const float4*)(Wq + (size_t)t * H_);
        float acc = bq[t];
#pragma unroll 8
        for (int k = 0; k < 128; k++) acc += dot4(hv[k], wq4[k]);
        qsh[t] = acc;
    }
    __syncthreads();

    // energy[t] = sum_a q[a] * key[b,a,t]
    const float* kp = key + (size_t)b * A_ * T_ + t;
    float e = 0.f;
#pragma unroll 8
    for (int a = 0; a < A_; a++) e += qsh[a] * kp[(size_t)a * T_];

    // masked softmax (max over ALL t, as in reference)
    red[t] = e;
    __syncthreads();
    for (int s = 256; s > 0; s >>= 1) {
        if (t < s) red[t] = fmaxf(red[t], red[t + s]);
        __syncthreads();
    }
    float m = red[0];
    __syncthreads();
    int len = src_lens[b];
    float p = (t < len) ? expf(e - m) : 0.f;
    red[t] = p;
    __syncthreads();
    for (int s = 256; s > 0; s >>= 1) {
        if (t < s) red[t] += red[t + s];
        __syncthreads();
    }
    att[b * T_ + t] = p / red[0];
}

// ------------------------------------------------- ctx[b,v] = sum_t att[t]*value[b,t,v]
__global__ void k_ctx(const float* __restrict__ att, const float* __restrict__ value,
                      float* __restrict__ ctx) {
    int b = blockIdx.x, v = threadIdx.x;
    __shared__ float ash[T_];
    ash[v] = att[b * T_ + v];
    __syncthreads();
    const float* vp = value + (size_t)b * T_ * VD_ + v;
    float acc = 0.f;
#pragma unroll 8
    for (int t = 0; t < T_; t++) acc += ash[t] * vp[(size_t)t * VD_];
    ctx[b * VD_ + v] = acc;
}

// ------------------------------------------------- proj = leaky_relu([c1,ctx1]@Wm^T+bm)
// grid 64 x 256 ; thread = (m_local<<5)|b
__global__ void k_proj(const float* __restrict__ c, const float* __restrict__ ctx,
                       const float* __restrict__ Wm, const float* __restrict__ bm,
                       float* __restrict__ proj) {
    int m = blockIdx.x * 8 + (threadIdx.x >> 5);
    int b = threadIdx.x & 31;
    const float4* c4 = (const float4*)(c + b * H_);
    const float4* x4 = (const float4*)(ctx + b * VD_);
    const float4* wa = (const float4*)(Wm + (size_t)m * 1024);
    const float4* wb = wa + 128;
    float acc = bm[m];
#pragma unroll 8
    for (int k = 0; k < 128; k++) acc += dot4(wa[k], c4[k]);
#pragma unroll 8
    for (int k = 0; k < 128; k++) acc += dot4(wb[k], x4[k]);
    proj[b * H_ + m] = (acc > 0.f) ? acc : 0.01f * acc;
}

// ------------------------------------------------- logits = proj@W_emb^T + b_proj
// grid 4000 x 256 ; thread = (b<<3)|v_local ; 8 v per block
__global__ void k_logits(const float* __restrict__ proj, const float* __restrict__ W_emb,
                         const float* __restrict__ b_proj, float* __restrict__ logits) {
    int b = threadIdx.x >> 3;
    int v = blockIdx.x * 8 + (threadIdx.x & 7);
    const float4* p4 = (const float4*)(proj + (size_t)b * H_);
    const float4* w4 = (const float4*)(W_emb + (size_t)v * H_);
    float acc = b_proj[v];
#pragma unroll 8
    for (int k = 0; k < 128; k++) acc += dot4(p4[k], w4[k]);
    logits[(size_t)b * V_ + v] = acc;
}

// ------------------------------------------------- per-row max/argmax + log-sum-exp
__global__ void k_lse(const float* __restrict__ logits, float* __restrict__ lse,
                      int* __restrict__ idx) {
    __shared__ float sm[1024];
    __shared__ int   si[1024];
    int b = blockIdx.x, t = threadIdx.x;
    const float* lp = logits + (size_t)b * V_;
    float m = -INFINITY;
    int mi = V_;
    for (int v = t; v < V_; v += 1024) {
        float x = lp[v];
        if (x > m) { m = x; mi = v; }
    }
    sm[t] = m; si[t] = mi;
    __syncthreads();
    for (int s = 512; s > 0; s >>= 1) {
        if (t < s) {
            float om = sm[t + s]; int oi = si[t + s];
            if (om > sm[t] || (om == sm[t] && oi < si[t])) { sm[t] = om; si[t] = oi; }
        }
        __syncthreads();
    }
    float M = sm[0];
    int   MI = si[0];
    __syncthreads();
    float s_ = 0.f;
    for (int v = t; v < V_; v += 1024) s_ += expf(lp[v] - M);
    sm[t] = s_;
    __syncthreads();
    for (int s = 512; s > 0; s >>= 1) {
        if (t < s) sm[t] += sm[t + s];
        __syncthreads();
    }
    if (t == 0) {
        lse[b] = M + logf(sm[0]);
        idx[b] = MI;
    }
}

// ------------------------------------------------- out[b,step,:] = logits - lse
__global__ void k_out(const float* __restrict__ logits, const float* __restrict__ lse,
                      float* __restrict__ out, int step, int L) {
    int g = blockIdx.x * 256 + threadIdx.x;
    if (g >= B_ * V_) return;
    int b = g / V_;
    int v = g - b * V_;
    out[((size_t)b * L + step) * V_ + v] = logits[g] - lse[b];
}

extern "C" void kernel_launch(void* const* d_in, const int* in_sizes, int n_in,
                              void* d_out, int out_size, void* d_ws, size_t ws_size,
                              hipStream_t stream) {
    const float* key      = (const float*)d_in[0];
    const float* value    = (const float*)d_in[1];
    // d_in[2] Yinput: unused (greedy decode), but its size gives L
    const int*   src_lens = (const int*)d_in[4];
    const float* W_emb    = (const float*)d_in[5];
    const float* b_proj   = (const float*)d_in[6];
    const float* Wq       = (const float*)d_in[7];
    const float* bq       = (const float*)d_in[8];
    const float* W_ih     = (const float*)d_in[9];
    const float* W_hh     = (const float*)d_in[10];
    const float* b_ih     = (const float*)d_in[11];
    const float* b_hh     = (const float*)d_in[12];
    const float* Wm       = (const float*)d_in[13];
    const float* bm       = (const float*)d_in[14];
    const float* h00      = (const float*)d_in[15];
    const float* c00      = (const float*)d_in[16];
    float* out = (float*)d_out;
    int L = in_sizes[2] / B_;

    float* ws = (float*)d_ws;
    float* h      = ws; ws += B_ * H_;
    float* c      = ws; ws += B_ * H_;
    float* ctx    = ws; ws += B_ * VD_;
    float* att    = ws; ws += B_ * T_;
    float* gates  = ws; ws += B_ * 4 * H_;
    float* proj   = ws; ws += B_ * H_;
    float* logits = ws; ws += (size_t)B_ * V_;
    float* lse    = ws; ws += B_;
    int*   idx    = (int*)ws;

    k_init<<<B_, H_, 0, stream>>>(h00, c00, h, c, idx);
    k_cell_att<<<B_, T_, 0, stream>>>(gates, h, c, Wq, bq, key, src_lens, att, 1);
    k_ctx<<<B_, VD_, 0, stream>>>(att, value, ctx);

    for (int s = 0; s < L; s++) {
        k_gates<<<256, 256, 0, stream>>>(W_emb, ctx, h, idx, W_ih, W_hh, b_ih, b_hh, gates);
        k_cell_att<<<B_, T_, 0, stream>>>(gates, h, c, Wq, bq, key, src_lens, att, 0);
        k_ctx<<<B_, VD_, 0, stream>>>(att, value, ctx);
        k_proj<<<64, 256, 0, stream>>>(c, ctx, Wm, bm, proj);
        k_logits<<<V_ / 8, 256, 0, stream>>>(proj, W_emb, b_proj, logits);
        k_lse<<<B_, 1024, 0, stream>>>(logits, lse, idx);
        k_out<<<(B_ * V_ + 255) / 256, 256, 0, stream>>>(logits, lse, out, s, L);
    }
}

// Round 3
// 37300.003 us; speedup vs baseline: 1.1877x; 1.1877x over previous
//
#include <hip/hip_runtime.h>
#include <math.h>

#define B_  32
#define T_  512
#define H_  512
#define A_  128
#define VD_ 512
#define V_  32000
#define GRID 256
#define NCHUNK 500   // 64-v logits chunks

__device__ __forceinline__ float sigf(float x){ return 1.f/(1.f+expf(-x)); }
__device__ __forceinline__ float dot4(float4 a, float4 b){ return a.x*b.x+a.y*b.y+a.z*b.z+a.w*b.w; }

struct DecArgs {
  const float *key, *value, *W_emb, *b_proj, *Wq, *bq, *W_ih, *W_hh, *b_ih, *b_hh, *Wm, *bm, *h00, *c00;
  const int* src_lens;
  float* out;
  float *hA, *hB, *c, *ctx, *proj, *logits, *lse, *pm, *ps;
  int *pidx, *idx;
  int* bar;   // [0..127] group counters (8 x stride16), [128] master, [144] gen
  int L;
};

// ---------------- device-scope two-level grid barrier (256 blocks) ----------
__device__ __forceinline__ void gbar(const DecArgs& P) {
  __syncthreads();
  if (threadIdx.x == 0) {
    int* gen = P.bar + 144;
    int g = __hip_atomic_load(gen, __ATOMIC_RELAXED, __HIP_MEMORY_SCOPE_AGENT);
    int grp = blockIdx.x & 7;
    int t = __hip_atomic_fetch_add(P.bar + grp*16, 1, __ATOMIC_ACQ_REL, __HIP_MEMORY_SCOPE_AGENT);
    bool released = false;
    if (t == 31) {                         // last of this 32-block group
      __hip_atomic_store(P.bar + grp*16, 0, __ATOMIC_RELAXED, __HIP_MEMORY_SCOPE_AGENT);
      int tm = __hip_atomic_fetch_add(P.bar + 128, 1, __ATOMIC_ACQ_REL, __HIP_MEMORY_SCOPE_AGENT);
      if (tm == 7) {                       // last group
        __hip_atomic_store(P.bar + 128, 0, __ATOMIC_RELAXED, __HIP_MEMORY_SCOPE_AGENT);
        __hip_atomic_fetch_add(gen, 1, __ATOMIC_RELEASE, __HIP_MEMORY_SCOPE_AGENT);
        released = true;
      }
    }
    if (!released) {
      while (__hip_atomic_load(gen, __ATOMIC_ACQUIRE, __HIP_MEMORY_SCOPE_AGENT) == g) {
        __builtin_amdgcn_s_sleep(2);
      }
    }
  }
  __syncthreads();
}

// ---------------- P1: gates + LSTM cell (all 256 blocks; block covers 2 t-cols)
__device__ __forceinline__ void phase_gates(const DecArgs& P, const float* hin, float* hout,
                                            int bid, int tid, float* sf) {
  int g = tid >> 6, tl = (tid >> 5) & 1, b = tid & 31;
  int t = bid*2 + tl;
  int j = g*512 + t;
  const float4* emb = (const float4*)(P.W_emb + (size_t)P.idx[b]*H_);
  const float4* cx  = (const float4*)(P.ctx + b*VD_);
  const float4* hv  = (const float4*)(hin + b*H_);
  const float4* wi  = (const float4*)(P.W_ih + (size_t)j*(H_+VD_));
  const float4* wc  = wi + 128;
  const float4* wh  = (const float4*)(P.W_hh + (size_t)j*H_);
  float acc = P.b_ih[j] + P.b_hh[j];
#pragma unroll 8
  for (int k = 0; k < 128; k++) acc += dot4(wi[k], emb[k]);
#pragma unroll 8
  for (int k = 0; k < 128; k++) acc += dot4(wc[k], cx[k]);
#pragma unroll 8
  for (int k = 0; k < 128; k++) acc += dot4(wh[k], hv[k]);
  sf[(tl*32 + b)*4 + g] = acc;
  __syncthreads();
  if (tid < 64) {
    int tl2 = tid >> 5, b2 = tid & 31;
    int t2 = bid*2 + tl2;
    float gi = sf[(tl2*32+b2)*4+0], gf = sf[(tl2*32+b2)*4+1];
    float gg = sf[(tl2*32+b2)*4+2], go = sf[(tl2*32+b2)*4+3];
    float c0 = P.c[b2*H_ + t2];
    float c1 = sigf(gf)*c0 + sigf(gi)*tanhf(gg);
    P.c[b2*H_ + t2] = c1;
    hout[b2*H_ + t2] = sigf(go)*tanhf(c1);
  }
}

// ---------------- out slice for (b,vs): out[b,sidx,:] = logits - lse
__device__ __forceinline__ void out_slice(const DecArgs& P, int bid, int tid, int sidx) {
  int b = bid & 31, vs = bid >> 5;
  float l = P.lse[b];
  const float4* lg = (const float4*)(P.logits + (size_t)b*V_ + vs*4000);
  float4* o4 = (float4*)(P.out + ((size_t)b*P.L + sidx)*V_ + vs*4000);
  for (int i = tid; i < 1000; i += 256) {
    float4 x = lg[i];
    o4[i] = make_float4(x.x-l, x.y-l, x.z-l, x.w-l);
  }
}

// ---------------- P2: q + energy + masked softmax (redundant x8) + ctx slice (+out s-1)
// block = vs*32 + b ; vs in 0..7 owns ctx columns [vs*64, vs*64+64)
__device__ __forceinline__ void phase_att_ctx(const DecArgs& P, const float* hsrc,
                                              int bid, int tid, float* sf, int sidx) {
  int b = bid & 31, vs = bid >> 5;
  float* h_sh   = sf;         // 512
  float* q_sh   = sf + 512;   // 128
  float* red    = sf + 640;   // 256
  float* att_sh = sf + 896;   // 512
  h_sh[tid]       = hsrc[b*H_ + tid];
  h_sh[tid + 256] = hsrc[b*H_ + tid + 256];
  __syncthreads();
  if (tid < 128) {
    const float4* hv = (const float4*)h_sh;
    const float4* w  = (const float4*)(P.Wq + (size_t)tid*H_);
    float acc = P.bq[tid];
#pragma unroll 8
    for (int k = 0; k < 128; k++) acc += dot4(w[k], hv[k]);
    q_sh[tid] = acc;
  }
  __syncthreads();
  const float* kp = P.key + (size_t)b*A_*T_;
  float e0 = 0.f, e1 = 0.f;
#pragma unroll 8
  for (int a = 0; a < A_; a++) {
    float qa = q_sh[a];
    e0 += qa * kp[a*T_ + tid];
    e1 += qa * kp[a*T_ + tid + 256];
  }
  red[tid] = fmaxf(e0, e1);
  __syncthreads();
  for (int s2 = 128; s2 > 0; s2 >>= 1) { if (tid < s2) red[tid] = fmaxf(red[tid], red[tid+s2]); __syncthreads(); }
  float M = red[0];
  __syncthreads();
  int len = P.src_lens[b];
  float p0 = (tid       < len) ? expf(e0 - M) : 0.f;
  float p1 = (tid + 256 < len) ? expf(e1 - M) : 0.f;
  red[tid] = p0 + p1;
  __syncthreads();
  for (int s2 = 128; s2 > 0; s2 >>= 1) { if (tid < s2) red[tid] += red[tid+s2]; __syncthreads(); }
  float S = red[0];
  __syncthreads();
  att_sh[tid]       = p0 / S;
  att_sh[tid + 256] = p1 / S;
  __syncthreads();
  // ctx slice: 64 v per block, 4-way t-split
  int vl = tid & 63, tq = tid >> 6;
  int v = vs*64 + vl;
  const float* vp = P.value + (size_t)b*T_*VD_ + v;
  float acc = 0.f;
  int t0 = tq*128;
#pragma unroll 8
  for (int t = t0; t < t0 + 128; t++) acc += att_sh[t] * vp[(size_t)t*VD_];
  red[tid] = acc;
  __syncthreads();
  if (tid < 64) P.ctx[b*VD_ + vs*64 + tid] = red[tid] + red[tid+64] + red[tid+128] + red[tid+192];
  if (sidx >= 0) out_slice(P, bid, tid, sidx);
}

// ---------------- P3: proj = leaky_relu([c1,ctx1]@Wm^T + bm)  (blocks 0..63)
__device__ __forceinline__ void phase_proj(const DecArgs& P, int bid, int tid) {
  if (bid < 64) {
    int m = bid*8 + (tid>>5), b = tid & 31;
    const float4* cv = (const float4*)(P.c + b*H_);
    const float4* xv = (const float4*)(P.ctx + b*VD_);
    const float4* wa = (const float4*)(P.Wm + (size_t)m*(H_+VD_));
    const float4* wb = wa + 128;
    float acc = P.bm[m];
#pragma unroll 8
    for (int k = 0; k < 128; k++) acc += dot4(wa[k], cv[k]);
#pragma unroll 8
    for (int k = 0; k < 128; k++) acc += dot4(wb[k], xv[k]);
    P.proj[b*H_ + m] = (acc > 0.f) ? acc : 0.01f*acc;
  }
}

// ---------------- P4: logits chunks (64 v) + per-chunk partial max/argmax/sumexp
__device__ __forceinline__ void phase_logits(const DecArgs& P, int bid, int tid,
                                             float* sf, int* si) {
  for (int vc = bid; vc < NCHUNK; vc += GRID) {
    int b = tid & 31, vl = tid >> 5;
    int vbase = vc*64 + vl*8;
    const float4* pv = (const float4*)(P.proj + b*H_);
    float acc[8];
#pragma unroll
    for (int i = 0; i < 8; i++) acc[i] = P.b_proj[vbase + i];
    const float4* w0 = (const float4*)(P.W_emb + (size_t)vbase*H_);
#pragma unroll 2
    for (int k = 0; k < 128; k++) {
      float4 p4 = pv[k];
#pragma unroll
      for (int i = 0; i < 8; i++) acc[i] += dot4(w0[i*128 + k], p4);
    }
    float4* lout = (float4*)(P.logits + (size_t)b*V_ + vbase);
    lout[0] = make_float4(acc[0],acc[1],acc[2],acc[3]);
    lout[1] = make_float4(acc[4],acc[5],acc[6],acc[7]);
    float m = acc[0]; int mi = 0;
#pragma unroll
    for (int i = 1; i < 8; i++) if (acc[i] > m) { m = acc[i]; mi = i; }
    float s = 0.f;
#pragma unroll
    for (int i = 0; i < 8; i++) s += expf(acc[i] - m);
    sf[vl*32 + b] = m;
    sf[256 + vl*32 + b] = s;
    si[vl*32 + b] = vbase + mi;
    __syncthreads();
    if (tid < 32) {
      int b2 = tid;
      float M = sf[b2], S = sf[256 + b2]; int I = si[b2];
      for (int v2 = 1; v2 < 8; v2++) {
        float m2 = sf[v2*32+b2], s2 = sf[256+v2*32+b2]; int i2 = si[v2*32+b2];
        if (m2 > M) { S = S*expf(M - m2) + s2; M = m2; I = i2; }
        else        { S += s2*expf(m2 - M); }     // ties keep earlier v
      }
      P.pm[vc*32 + b2] = M;
      P.ps[vc*32 + b2] = S;
      P.pidx[vc*32 + b2] = I;
    }
    __syncthreads();
  }
}

// ---------------- P5: merge chunk partials -> lse[b], idx[b]  (blocks 0..31)
__device__ __forceinline__ void phase_merge(const DecArgs& P, int bid, int tid,
                                            float* sf, int* si) {
  if (bid < B_) {
    int b = bid;
    float M = P.pm[tid*32 + b], S = P.ps[tid*32 + b]; int I = P.pidx[tid*32 + b];
    int c2 = tid + 256;
    if (c2 < NCHUNK) {
      float m2 = P.pm[c2*32+b], s2 = P.ps[c2*32+b]; int i2 = P.pidx[c2*32+b];
      if (m2 > M)      { S = S*expf(M - m2) + s2; M = m2; I = i2; }
      else if (m2 == M){ S += s2; I = min(I, i2); }
      else             { S += s2*expf(m2 - M); }
    }
    sf[tid] = M; sf[256+tid] = S; si[tid] = I;
    __syncthreads();
    for (int st = 128; st > 0; st >>= 1) {
      if (tid < st) {
        float m1 = sf[tid], s1 = sf[256+tid]; int i1 = si[tid];
        float m2 = sf[tid+st], s2 = sf[256+tid+st]; int i2 = si[tid+st];
        float Mn, Sn; int In;
        if (m2 > m1)      { Mn = m2; Sn = s1*expf(m1-m2) + s2; In = i2; }
        else if (m2 < m1) { Mn = m1; Sn = s1 + s2*expf(m2-m1); In = i1; }
        else              { Mn = m1; Sn = s1 + s2; In = min(i1, i2); }
        sf[tid] = Mn; sf[256+tid] = Sn; si[tid] = In;
      }
      __syncthreads();
    }
    if (tid == 0) { P.lse[b] = sf[0] + logf(sf[256]); P.idx[b] = si[0]; }
  }
}

__global__ __launch_bounds__(256) void k_decode(DecArgs P) {
  const int bid = blockIdx.x, tid = threadIdx.x;
  __shared__ float sf[1536];
  __shared__ int   si[256];

  // init h, c, idx
  {
    int g = bid*256 + tid;
    if (g < B_*H_) { int j = g & (H_-1); P.hA[g] = P.h00[j]; P.c[g] = P.c00[j]; }
    if (g < B_) P.idx[g] = 0;
  }
  gbar(P);

  // prologue attend with h0 -> ctx
  phase_att_ctx(P, P.hA, bid, tid, sf, -1);
  gbar(P);

  for (int s = 0; s < P.L; ++s) {
    const float* hin  = (s & 1) ? P.hB : P.hA;
    float*       hout = (s & 1) ? P.hA : P.hB;
    phase_gates(P, hin, hout, bid, tid, sf);
    gbar(P);
    phase_att_ctx(P, hout, bid, tid, sf, s - 1);   // + out[s-1]
    gbar(P);
    phase_proj(P, bid, tid);
    gbar(P);
    phase_logits(P, bid, tid, sf, si);
    gbar(P);
    phase_merge(P, bid, tid, sf, si);
    gbar(P);
  }
  out_slice(P, bid, tid, P.L - 1);
}

extern "C" void kernel_launch(void* const* d_in, const int* in_sizes, int n_in,
                              void* d_out, int out_size, void* d_ws, size_t ws_size,
                              hipStream_t stream) {
  DecArgs P;
  P.key      = (const float*)d_in[0];
  P.value    = (const float*)d_in[1];
  P.src_lens = (const int*)d_in[4];
  P.W_emb    = (const float*)d_in[5];
  P.b_proj   = (const float*)d_in[6];
  P.Wq       = (const float*)d_in[7];
  P.bq       = (const float*)d_in[8];
  P.W_ih     = (const float*)d_in[9];
  P.W_hh     = (const float*)d_in[10];
  P.b_ih     = (const float*)d_in[11];
  P.b_hh     = (const float*)d_in[12];
  P.Wm       = (const float*)d_in[13];
  P.bm       = (const float*)d_in[14];
  P.h00      = (const float*)d_in[15];
  P.c00      = (const float*)d_in[16];
  P.out      = (float*)d_out;
  P.L        = in_sizes[2] / B_;

  P.bar = (int*)d_ws;                      // 160 ints (groups, master, gen)
  float* ws = (float*)d_ws + 160;
  P.hA     = ws; ws += B_*H_;
  P.hB     = ws; ws += B_*H_;
  P.c      = ws; ws += B_*H_;
  P.ctx    = ws; ws += B_*VD_;
  P.proj   = ws; ws += B_*H_;
  P.lse    = ws; ws += 32;
  P.pm     = ws; ws += NCHUNK*B_;
  P.ps     = ws; ws += NCHUNK*B_;
  P.logits = ws; ws += (size_t)B_*V_;
  P.pidx   = (int*)ws; ws += NCHUNK*B_;
  P.idx    = (int*)ws;

  hipMemsetAsync(P.bar, 0, 160*sizeof(int), stream);
  hipLaunchKernelGGL(k_decode, dim3(GRID), dim3(256), 0, stream, P);
}